// Round 1
// baseline (729.115 us; speedup 1.0000x reference)
//
#include <hip/hip_runtime.h>
#include <math.h>
#include <float.h>

#define NN 32768
#define NE 524288
#define NG 256
#define DD 64
#define NL 4
#define AVGDLOG 2.8332133340562162f
#define BN_EPS 1e-5f

// ---------------- init kernels ----------------

__global__ void k_embed(const int* __restrict__ h_tok, const float* __restrict__ emb_h,
                        float* __restrict__ h) {
    int t = blockIdx.x * 256 + threadIdx.x;   // NN*DD threads
    int n = t >> 6, j = t & 63;
    h[t] = emb_h[h_tok[n] * DD + j];
}

__global__ void k_deg(const int* __restrict__ dst, int* __restrict__ deg) {
    int e = blockIdx.x * 256 + threadIdx.x;
    if (e < NE) atomicAdd(&deg[dst[e]], 1);
}

__global__ __launch_bounds__(1024) void k_scan(const int* __restrict__ deg,
                                               int* __restrict__ row_start,
                                               int* __restrict__ cursor,
                                               float* __restrict__ amp,
                                               float* __restrict__ att,
                                               float* __restrict__ invdeg) {
    __shared__ int sd[1024];
    int t = threadIdx.x;
    int base = t * 32;
    int loc[32];
    int s = 0;
#pragma unroll
    for (int i = 0; i < 32; i++) { loc[i] = deg[base + i]; s += loc[i]; }
    sd[t] = s;
    __syncthreads();
    for (int off = 1; off < 1024; off <<= 1) {
        int v = (t >= off) ? sd[t - off] : 0;
        __syncthreads();
        sd[t] += v;
        __syncthreads();
    }
    int run = sd[t] - s;   // exclusive prefix
#pragma unroll
    for (int i = 0; i < 32; i++) {
        int idx = base + i;
        row_start[idx] = run;
        cursor[idx] = run;
        int dg = loc[i];
        float d = (float)dg;
        float logd = logf(d + 1.0f);
        amp[idx] = logd * (1.0f / AVGDLOG);
        att[idx] = AVGDLOG / fmaxf(logd, 1e-6f);
        invdeg[idx] = 1.0f / fmaxf(d, 1.0f);
        run += dg;
    }
    if (t == 1023) row_start[NN] = run;
}

__global__ void k_scatter(const int* __restrict__ src, const int* __restrict__ dst,
                          const int* __restrict__ e_tok, int* __restrict__ cursor,
                          int* __restrict__ csr) {
    int e = blockIdx.x * 256 + threadIdx.x;
    int d = dst[e];
    int p = atomicAdd(&cursor[d], 1);
    csr[p] = (src[e] << 3) | (e_tok[e] & 7);
}

// bond_msg[l][r][j] = b_pre[l][j] + sum_k emb_e[r][k] * W_pre[l][128+k][j]
__global__ void k_bond(const float* __restrict__ emb_e, const float* __restrict__ W_pre,
                       const float* __restrict__ b_pre, float* __restrict__ bond) {
    int t = blockIdx.x * 256 + threadIdx.x;   // NL*8*64 = 2048 threads
    int j = t & 63, r = (t >> 6) & 7, l = t >> 9;
    float s = b_pre[l * DD + j];
    const float* w = W_pre + (size_t)l * 192 * DD + 128 * DD + j;
    const float* e = emb_e + r * DD;
#pragma unroll
    for (int k = 0; k < DD; k++) s = fmaf(e[k], w[k * DD], s);
    bond[t] = s;
}

// ---------------- per-layer kernels ----------------

// A: ts = h@Wpre[0:64], td = h@Wpre[64:128], base = h@Wpost[0:64]
__global__ __launch_bounds__(256) void k_A(const float* __restrict__ h,
                                           const float* __restrict__ W_pre,
                                           const float* __restrict__ W_post, int l,
                                           float* __restrict__ ts, float* __restrict__ td,
                                           float* __restrict__ base_o) {
    __shared__ float Ws0[DD * DD];
    __shared__ float Ws1[DD * DD];
    __shared__ float Ws2[DD * DD];
    __shared__ float hs[64][DD];
    int t = threadIdx.x;
    int j = t & 63, q = t >> 6;
    int n0 = blockIdx.x * 64;
    const float* Wsrc0 = W_pre + (size_t)l * 192 * DD;
    const float* Wsrc1 = W_pre + (size_t)l * 192 * DD + 64 * DD;
    const float* Wsrc2 = W_post + (size_t)l * 832 * DD;
#pragma unroll
    for (int p = 0; p < 16; p++) {
        int row = p * 4 + q;
        Ws0[row * DD + j] = Wsrc0[row * DD + j];
        Ws1[row * DD + j] = Wsrc1[row * DD + j];
        Ws2[row * DD + j] = Wsrc2[row * DD + j];
        hs[row][j] = h[(size_t)(n0 + row) * DD + j];
    }
    __syncthreads();
    float a0[16], a1[16], a2[16];
#pragma unroll
    for (int i = 0; i < 16; i++) { a0[i] = 0.f; a1[i] = 0.f; a2[i] = 0.f; }
    float ab[16][4];
#pragma unroll
    for (int k4 = 0; k4 < 16; k4++) {
#pragma unroll
        for (int i = 0; i < 16; i++) {
            float4 v = *(const float4*)&hs[q * 16 + i][k4 * 4];
            ab[i][0] = v.x; ab[i][1] = v.y; ab[i][2] = v.z; ab[i][3] = v.w;
        }
#pragma unroll
        for (int d = 0; d < 4; d++) {
            int k = k4 * 4 + d;
            float w0 = Ws0[k * DD + j];
            float w1 = Ws1[k * DD + j];
            float w2 = Ws2[k * DD + j];
#pragma unroll
            for (int i = 0; i < 16; i++) {
                a0[i] = fmaf(ab[i][d], w0, a0[i]);
                a1[i] = fmaf(ab[i][d], w1, a1[i]);
                a2[i] = fmaf(ab[i][d], w2, a2[i]);
            }
        }
    }
#pragma unroll
    for (int i = 0; i < 16; i++) {
        size_t n = (size_t)(n0 + q * 16 + i);
        ts[n * DD + j] = a0[i];
        td[n * DD + j] = a1[i];
        base_o[n * DD + j] = a2[i];
    }
}

// B: per-node aggregation (one wave per node, lane = feature)
__global__ __launch_bounds__(256) void k_B(const float* __restrict__ ts,
                                           const float* __restrict__ td,
                                           const float* __restrict__ bond_l,
                                           const int* __restrict__ row_start,
                                           const int* __restrict__ csr,
                                           const float* __restrict__ invdeg,
                                           float* __restrict__ agg) {
    __shared__ float bs[8 * DD];
    int t = threadIdx.x;
    bs[t] = bond_l[t];
    bs[256 + t] = bond_l[256 + t];
    __syncthreads();
    int lane = t & 63;
    int n = blockIdx.x * 4 + (t >> 6);
    int rs = row_start[n], re = row_start[n + 1];
    int cnt = re - rs;
    float tdv = td[(size_t)n * DD + lane];
    float s1 = 0.f, s2 = 0.f, mx = -FLT_MAX, mn = FLT_MAX;
    for (int b0 = 0; b0 < cnt; b0 += 64) {
        int nb = min(64, cnt - b0);
        int pk = (lane < nb) ? csr[rs + b0 + lane] : 0;
        int i = 0;
        for (; i + 4 <= nb; i += 4) {
            int p0 = __shfl(pk, i), p1 = __shfl(pk, i + 1);
            int p2 = __shfl(pk, i + 2), p3 = __shfl(pk, i + 3);
            float m0 = ts[(size_t)(p0 >> 3) * DD + lane] + bs[(p0 & 7) * DD + lane];
            float m1 = ts[(size_t)(p1 >> 3) * DD + lane] + bs[(p1 & 7) * DD + lane];
            float m2 = ts[(size_t)(p2 >> 3) * DD + lane] + bs[(p2 & 7) * DD + lane];
            float m3 = ts[(size_t)(p3 >> 3) * DD + lane] + bs[(p3 & 7) * DD + lane];
            m0 += tdv; m1 += tdv; m2 += tdv; m3 += tdv;
            s1 += m0; s2 = fmaf(m0, m0, s2); mx = fmaxf(mx, m0); mn = fminf(mn, m0);
            s1 += m1; s2 = fmaf(m1, m1, s2); mx = fmaxf(mx, m1); mn = fminf(mn, m1);
            s1 += m2; s2 = fmaf(m2, m2, s2); mx = fmaxf(mx, m2); mn = fminf(mn, m2);
            s1 += m3; s2 = fmaf(m3, m3, s2); mx = fmaxf(mx, m3); mn = fminf(mn, m3);
        }
        for (; i < nb; i++) {
            int p0 = __shfl(pk, i);
            float m0 = ts[(size_t)(p0 >> 3) * DD + lane] + bs[(p0 & 7) * DD + lane] + tdv;
            s1 += m0; s2 = fmaf(m0, m0, s2); mx = fmaxf(mx, m0); mn = fminf(mn, m0);
        }
    }
    float iv = invdeg[n];
    float mean = s1 * iv;
    float var = fmaxf(s2 * iv - mean * mean, 0.f);
    float sd = sqrtf(var + BN_EPS);
    bool has = cnt > 0;
    mx = has ? mx : 0.f;
    mn = has ? mn : 0.f;
    float* ao = agg + (size_t)n * 256;
    ao[lane] = mean;
    ao[64 + lane] = mx;
    ao[128 + lane] = mn;
    ao[192 + lane] = sd;
}

// C: h_pre = (base + b_post + agg@W1c + amp*(agg@W2c) + att*(agg@W3c)) * snorm ; BN partial sums
__global__ __launch_bounds__(256) void k_C(const float* __restrict__ agg,
                                           const float* __restrict__ base_i,
                                           const float* __restrict__ W_post,
                                           const float* __restrict__ b_post, int l,
                                           const float* __restrict__ amp,
                                           const float* __restrict__ att,
                                           const float* __restrict__ snorm,
                                           float* __restrict__ h_pre,
                                           float* __restrict__ bn_acc) {
    __shared__ float Ws0[DD * DD];
    __shared__ float Ws1[DD * DD];
    __shared__ float Ws2[DD * DD];
    __shared__ float ags[64][DD];
    int t = threadIdx.x;
    int j = t & 63, q = t >> 6;
    int n0 = blockIdx.x * 64;
    const float* Wp = W_post + (size_t)l * 832 * DD;
    float a1[16], a2[16], a3[16];
#pragma unroll
    for (int i = 0; i < 16; i++) { a1[i] = 0.f; a2[i] = 0.f; a3[i] = 0.f; }
    float ab[16][4];
    for (int kc = 0; kc < 4; kc++) {
        __syncthreads();
#pragma unroll
        for (int p = 0; p < 16; p++) {
            int row = p * 4 + q;          // 0..63 within chunk
            int gk = kc * 64 + row;       // 0..255
            Ws0[row * DD + j] = Wp[(size_t)(64 + gk) * DD + j];
            Ws1[row * DD + j] = Wp[(size_t)(320 + gk) * DD + j];
            Ws2[row * DD + j] = Wp[(size_t)(576 + gk) * DD + j];
            ags[row][j] = agg[(size_t)(n0 + row) * 256 + kc * 64 + j];
        }
        __syncthreads();
#pragma unroll
        for (int k4 = 0; k4 < 16; k4++) {
#pragma unroll
            for (int i = 0; i < 16; i++) {
                float4 v = *(const float4*)&ags[q * 16 + i][k4 * 4];
                ab[i][0] = v.x; ab[i][1] = v.y; ab[i][2] = v.z; ab[i][3] = v.w;
            }
#pragma unroll
            for (int d = 0; d < 4; d++) {
                int k = k4 * 4 + d;
                float w1 = Ws0[k * DD + j];
                float w2 = Ws1[k * DD + j];
                float w3 = Ws2[k * DD + j];
#pragma unroll
                for (int i = 0; i < 16; i++) {
                    a1[i] = fmaf(ab[i][d], w1, a1[i]);
                    a2[i] = fmaf(ab[i][d], w2, a2[i]);
                    a3[i] = fmaf(ab[i][d], w3, a3[i]);
                }
            }
        }
    }
    float bp = b_post[l * DD + j];
    float ps = 0.f, pss = 0.f;
#pragma unroll
    for (int i = 0; i < 16; i++) {
        int n = n0 + q * 16 + i;
        float o = base_i[(size_t)n * DD + j] + bp + a1[i] + amp[n] * a2[i] + att[n] * a3[i];
        o *= snorm[n];
        h_pre[(size_t)n * DD + j] = o;
        ps += o;
        pss = fmaf(o, o, pss);
    }
    __syncthreads();
    float* red = &ags[0][0];   // reuse LDS (needs 512 floats)
    red[q * 64 + j] = ps;
    red[256 + q * 64 + j] = pss;
    __syncthreads();
    if (t < 64) {
        float s = red[t] + red[64 + t] + red[128 + t] + red[192 + t];
        float s2 = red[256 + t] + red[320 + t] + red[384 + t] + red[448 + t];
        atomicAdd(&bn_acc[l * 128 + t], s);
        atomicAdd(&bn_acc[l * 128 + 64 + t], s2);
    }
}

// D: batchnorm finalize + relu + residual (in-place into h)
__global__ void k_D(const float* __restrict__ h_pre, const float* __restrict__ bn_acc, int l,
                    const float* __restrict__ gamma, const float* __restrict__ beta,
                    float* __restrict__ h) {
    int t = blockIdx.x * 256 + threadIdx.x;   // NN*DD
    int j = t & 63;
    float mu = bn_acc[l * 128 + j] * (1.0f / NN);
    float var = bn_acc[l * 128 + 64 + j] * (1.0f / NN) - mu * mu;
    float inv = rsqrtf(var + BN_EPS);
    float v = gamma[l * DD + j] * (h_pre[t] - mu) * inv + beta[l * DD + j];
    v = fmaxf(v, 0.f);
    h[t] = h[t] + v;
}

// readout: per-graph mean (128 consecutive nodes) + MLP 64->32->16->1
__global__ __launch_bounds__(64) void k_read(const float* __restrict__ h,
                                             const float* __restrict__ W1, const float* __restrict__ b1,
                                             const float* __restrict__ W2, const float* __restrict__ b2,
                                             const float* __restrict__ W3, const float* __restrict__ b3,
                                             float* __restrict__ out) {
    __shared__ float hgs[64];
    __shared__ float o1[32];
    __shared__ float o2[16];
    int g = blockIdx.x, lane = threadIdx.x;
    float acc = 0.f;
    for (int i = 0; i < 128; i++) acc += h[(size_t)(g * 128 + i) * DD + lane];
    hgs[lane] = acc * (1.0f / 128.0f);
    __syncthreads();
    if (lane < 32) {
        float s = b1[lane];
#pragma unroll
        for (int k = 0; k < 64; k++) s = fmaf(hgs[k], W1[k * 32 + lane], s);
        o1[lane] = fmaxf(s, 0.f);
    }
    __syncthreads();
    if (lane < 16) {
        float s = b2[lane];
#pragma unroll
        for (int k = 0; k < 32; k++) s = fmaf(o1[k], W2[k * 16 + lane], s);
        o2[lane] = fmaxf(s, 0.f);
    }
    __syncthreads();
    if (lane == 0) {
        float s = b3[0];
#pragma unroll
        for (int k = 0; k < 16; k++) s = fmaf(o2[k], W3[k], s);
        out[g] = s;
    }
}

// ---------------- launch ----------------

extern "C" void kernel_launch(void* const* d_in, const int* in_sizes, int n_in,
                              void* d_out, int out_size, void* d_ws, size_t ws_size,
                              hipStream_t stream) {
    const int* h_tok = (const int*)d_in[0];
    const int* e_tok = (const int*)d_in[1];
    const int* src = (const int*)d_in[2];
    const int* dst = (const int*)d_in[3];
    // d_in[4] graph_id: structure known (n/128)
    const float* snorm = (const float*)d_in[5];
    const float* emb_h = (const float*)d_in[6];
    const float* emb_e = (const float*)d_in[7];
    const float* W_pre = (const float*)d_in[8];
    const float* b_pre = (const float*)d_in[9];
    const float* W_post = (const float*)d_in[10];
    const float* b_post = (const float*)d_in[11];
    const float* gamma = (const float*)d_in[12];
    const float* beta = (const float*)d_in[13];
    const float* W1 = (const float*)d_in[14];
    const float* b1 = (const float*)d_in[15];
    const float* W2 = (const float*)d_in[16];
    const float* b2 = (const float*)d_in[17];
    const float* W3 = (const float*)d_in[18];
    const float* b3 = (const float*)d_in[19];
    float* out = (float*)d_out;

    char* ws = (char*)d_ws;
    size_t off = 0;
    auto alloc = [&](size_t bytes) {
        void* p = ws + off;
        off += (bytes + 255) & ~(size_t)255;
        return p;
    };
    float* h_cur = (float*)alloc((size_t)NN * DD * 4);
    float* h_pre = (float*)alloc((size_t)NN * DD * 4);
    float* ts = (float*)alloc((size_t)NN * DD * 4);
    float* td = (float*)alloc((size_t)NN * DD * 4);
    float* base_b = (float*)alloc((size_t)NN * DD * 4);
    float* agg = (float*)alloc((size_t)NN * 256 * 4);
    int* deg = (int*)alloc((size_t)NN * 4);
    int* row_start = (int*)alloc((size_t)(NN + 1) * 4);
    int* cursor = (int*)alloc((size_t)NN * 4);
    int* csr = (int*)alloc((size_t)NE * 4);
    float* amp = (float*)alloc((size_t)NN * 4);
    float* att = (float*)alloc((size_t)NN * 4);
    float* invdeg = (float*)alloc((size_t)NN * 4);
    float* bond = (float*)alloc((size_t)NL * 8 * DD * 4);
    float* bn_acc = (float*)alloc((size_t)NL * 128 * 4);

    hipMemsetAsync(deg, 0, (size_t)NN * 4, stream);
    hipMemsetAsync(bn_acc, 0, (size_t)NL * 128 * 4, stream);

    k_embed<<<NN * DD / 256, 256, 0, stream>>>(h_tok, emb_h, h_cur);
    k_deg<<<NE / 256, 256, 0, stream>>>(dst, deg);
    k_scan<<<1, 1024, 0, stream>>>(deg, row_start, cursor, amp, att, invdeg);
    k_scatter<<<NE / 256, 256, 0, stream>>>(src, dst, e_tok, cursor, csr);
    k_bond<<<NL * 8 * DD / 256, 256, 0, stream>>>(emb_e, W_pre, b_pre, bond);

    for (int l = 0; l < NL; l++) {
        k_A<<<NN / 64, 256, 0, stream>>>(h_cur, W_pre, W_post, l, ts, td, base_b);
        k_B<<<NN / 4, 256, 0, stream>>>(ts, td, bond + l * 8 * DD, row_start, csr, invdeg, agg);
        k_C<<<NN / 64, 256, 0, stream>>>(agg, base_b, W_post, b_post, l, amp, att, snorm,
                                         h_pre, bn_acc);
        k_D<<<NN * DD / 256, 256, 0, stream>>>(h_pre, bn_acc, l, gamma, beta, h_cur);
    }
    k_read<<<NG, 64, 0, stream>>>(h_cur, W1, b1, W2, b2, W3, b3, out);
}

// Round 2
// 543.337 us; speedup vs baseline: 1.3419x; 1.3419x over previous
//
#include <hip/hip_runtime.h>
#include <math.h>
#include <float.h>

#define NN 32768
#define NE 524288
#define NG 256
#define DD 64
#define NL 4
#define AVGDLOG 2.8332133340562162f
#define BN_EPS 1e-5f

// ---------------- init kernels ----------------

__global__ void k_embed(const int* __restrict__ h_tok, const float* __restrict__ emb_h,
                        float* __restrict__ h) {
    int t = blockIdx.x * 256 + threadIdx.x;   // NN*DD threads
    int n = t >> 6, j = t & 63;
    h[t] = emb_h[h_tok[n] * DD + j];
}

__global__ void k_deg(const int* __restrict__ dst, int* __restrict__ deg) {
    int e = blockIdx.x * 256 + threadIdx.x;
    if (e < NE) atomicAdd(&deg[dst[e]], 1);
}

__global__ __launch_bounds__(1024) void k_scan(const int* __restrict__ deg,
                                               int* __restrict__ row_start,
                                               int* __restrict__ cursor,
                                               float* __restrict__ amp,
                                               float* __restrict__ att,
                                               float* __restrict__ invdeg) {
    __shared__ int sd[1024];
    int t = threadIdx.x;
    int base = t * 32;
    int loc[32];
    int s = 0;
#pragma unroll
    for (int i = 0; i < 32; i++) { loc[i] = deg[base + i]; s += loc[i]; }
    sd[t] = s;
    __syncthreads();
    for (int off = 1; off < 1024; off <<= 1) {
        int v = (t >= off) ? sd[t - off] : 0;
        __syncthreads();
        sd[t] += v;
        __syncthreads();
    }
    int run = sd[t] - s;   // exclusive prefix
#pragma unroll
    for (int i = 0; i < 32; i++) {
        int idx = base + i;
        row_start[idx] = run;
        cursor[idx] = run;
        int dg = loc[i];
        float d = (float)dg;
        float logd = logf(d + 1.0f);
        amp[idx] = logd * (1.0f / AVGDLOG);
        att[idx] = AVGDLOG / fmaxf(logd, 1e-6f);
        invdeg[idx] = 1.0f / fmaxf(d, 1.0f);
        run += dg;
    }
    if (t == 1023) row_start[NN] = run;
}

__global__ void k_scatter(const int* __restrict__ src, const int* __restrict__ dst,
                          const int* __restrict__ e_tok, int* __restrict__ cursor,
                          int* __restrict__ csr) {
    int e = blockIdx.x * 256 + threadIdx.x;
    int d = dst[e];
    int p = atomicAdd(&cursor[d], 1);
    csr[p] = (src[e] << 3) | (e_tok[e] & 7);
}

// bond_msg[l][r][j] = b_pre[l][j] + sum_k emb_e[r][k] * W_pre[l][128+k][j]
__global__ void k_bond(const float* __restrict__ emb_e, const float* __restrict__ W_pre,
                       const float* __restrict__ b_pre, float* __restrict__ bond) {
    int t = blockIdx.x * 256 + threadIdx.x;   // NL*8*64 = 2048 threads
    int j = t & 63, r = (t >> 6) & 7, l = t >> 9;
    float s = b_pre[l * DD + j];
    const float* w = W_pre + (size_t)l * 192 * DD + 128 * DD + j;
    const float* e = emb_e + r * DD;
#pragma unroll
    for (int k = 0; k < DD; k++) s = fmaf(e[k], w[k * DD], s);
    bond[t] = s;
}

// ---------------- per-layer kernels ----------------
// Shared design for k_A / k_C:
//  - 512 threads (8 waves), 64 nodes/block, 8 nodes per thread, col j = t&63
//  - W tile transposed+XOR-swizzled in LDS, read as one ds_read_b128 per chunk
//    (lanes j, j+16, j+32, j+48 broadcast same addr; remaining aliasing 2-way = free)
//  - A-operand (h / agg rows) is wave-uniform: addresses built from
//    readfirstlane'd wave id -> scalar (s_load) / broadcast loads, no LDS
// LDS swizzle: element (c, k, j) stored at c*4096 + j*64 + ((((k>>2)^ (j&15))<<2)|(k&3))

// A: ts = h@Wpre[0:64], td = h@Wpre[64:128], base = h@Wpost[0:64]
__global__ __launch_bounds__(512, 4) void k_A(const float* __restrict__ h,
                                              const float* __restrict__ W_pre,
                                              const float* __restrict__ W_post, int l,
                                              float* __restrict__ ts, float* __restrict__ td,
                                              float* __restrict__ base_o) {
    __shared__ float wlds[12288];
    int t = threadIdx.x;
    int j = t & 63;
    int jm = j & 15;
    int q = __builtin_amdgcn_readfirstlane(t >> 6);
    int n0 = blockIdx.x * 64;
    const float* W0 = W_pre + (size_t)l * 192 * DD;
    const float* W1 = W0 + 64 * DD;
    const float* W2 = W_post + (size_t)l * 832 * DD;
#pragma unroll
    for (int p = 0; p < 24; ++p) {
        int c = p >> 3;
        int k = ((p & 7) << 3) + (t >> 6);
        const float* Wc = (c == 0) ? W0 : (c == 1 ? W1 : W2);
        wlds[c * 4096 + j * 64 + ((((k >> 2) ^ jm) << 2) | (k & 3))] = Wc[(size_t)k * 64 + j];
    }
    float a0[8], a1[8], a2[8];
#pragma unroll
    for (int i = 0; i < 8; ++i) { a0[i] = 0.f; a1[i] = 0.f; a2[i] = 0.f; }
    __syncthreads();
    const float* hp = h + (size_t)(n0 + q * 8) * DD;
#pragma unroll 4
    for (int k4 = 0; k4 < 16; ++k4) {
        int widx = j * 64 + ((k4 ^ jm) << 2);
        float4 w0 = *(const float4*)&wlds[widx];
        float4 w1 = *(const float4*)&wlds[4096 + widx];
        float4 w2 = *(const float4*)&wlds[8192 + widx];
#pragma unroll
        for (int i = 0; i < 8; ++i) {
            float4 a = *(const float4*)(hp + (size_t)i * DD + (k4 << 2));
            a0[i] = fmaf(a.w, w0.w, fmaf(a.z, w0.z, fmaf(a.y, w0.y, fmaf(a.x, w0.x, a0[i]))));
            a1[i] = fmaf(a.w, w1.w, fmaf(a.z, w1.z, fmaf(a.y, w1.y, fmaf(a.x, w1.x, a1[i]))));
            a2[i] = fmaf(a.w, w2.w, fmaf(a.z, w2.z, fmaf(a.y, w2.y, fmaf(a.x, w2.x, a2[i]))));
        }
    }
#pragma unroll
    for (int i = 0; i < 8; ++i) {
        size_t n = (size_t)(n0 + q * 8 + i);
        ts[n * DD + j] = a0[i];
        td[n * DD + j] = a1[i];
        base_o[n * DD + j] = a2[i];
    }
}

// B: per-node aggregation (one wave per node, lane = feature)
__global__ __launch_bounds__(256) void k_B(const float* __restrict__ ts,
                                           const float* __restrict__ td,
                                           const float* __restrict__ bond_l,
                                           const int* __restrict__ row_start,
                                           const int* __restrict__ csr,
                                           const float* __restrict__ invdeg,
                                           float* __restrict__ agg) {
    int t = threadIdx.x;
    int lane = t & 63;
    int q = __builtin_amdgcn_readfirstlane(t >> 6);
    int n = blockIdx.x * 4 + q;
    int rs = __builtin_amdgcn_readfirstlane(row_start[n]);
    int re = __builtin_amdgcn_readfirstlane(row_start[n + 1]);
    int cnt = re - rs;
    const int* cp = csr + rs;
    float tdv = td[(size_t)n * DD + lane];
    float s1 = 0.f, s2 = 0.f, mx = -FLT_MAX, mn = FLT_MAX;
    int i = 0;
    for (; i + 4 <= cnt; i += 4) {
        int p0 = cp[i], p1 = cp[i + 1], p2 = cp[i + 2], p3 = cp[i + 3];
        float m0 = ts[(size_t)(p0 >> 3) * DD + lane] + bond_l[((p0 & 7) << 6) + lane];
        float m1 = ts[(size_t)(p1 >> 3) * DD + lane] + bond_l[((p1 & 7) << 6) + lane];
        float m2 = ts[(size_t)(p2 >> 3) * DD + lane] + bond_l[((p2 & 7) << 6) + lane];
        float m3 = ts[(size_t)(p3 >> 3) * DD + lane] + bond_l[((p3 & 7) << 6) + lane];
        m0 += tdv; m1 += tdv; m2 += tdv; m3 += tdv;
        s1 += m0; s2 = fmaf(m0, m0, s2); mx = fmaxf(mx, m0); mn = fminf(mn, m0);
        s1 += m1; s2 = fmaf(m1, m1, s2); mx = fmaxf(mx, m1); mn = fminf(mn, m1);
        s1 += m2; s2 = fmaf(m2, m2, s2); mx = fmaxf(mx, m2); mn = fminf(mn, m2);
        s1 += m3; s2 = fmaf(m3, m3, s2); mx = fmaxf(mx, m3); mn = fminf(mn, m3);
    }
    for (; i < cnt; i++) {
        int p0 = cp[i];
        float m0 = ts[(size_t)(p0 >> 3) * DD + lane] + bond_l[((p0 & 7) << 6) + lane] + tdv;
        s1 += m0; s2 = fmaf(m0, m0, s2); mx = fmaxf(mx, m0); mn = fminf(mn, m0);
    }
    float iv = invdeg[n];
    float mean = s1 * iv;
    float var = fmaxf(s2 * iv - mean * mean, 0.f);
    float sd = sqrtf(var + BN_EPS);
    bool has = cnt > 0;
    mx = has ? mx : 0.f;
    mn = has ? mn : 0.f;
    float* ao = agg + (size_t)n * 256;
    ao[lane] = mean;
    ao[64 + lane] = mx;
    ao[128 + lane] = mn;
    ao[192 + lane] = sd;
}

// C: h_pre = (base + b_post + agg@W1c + amp*(agg@W2c) + att*(agg@W3c)) * snorm ; BN partials
__global__ __launch_bounds__(512, 4) void k_C(const float* __restrict__ agg,
                                              const float* __restrict__ base_i,
                                              const float* __restrict__ W_post,
                                              const float* __restrict__ b_post, int l,
                                              const float* __restrict__ amp,
                                              const float* __restrict__ att,
                                              const float* __restrict__ snorm,
                                              float* __restrict__ h_pre,
                                              float* __restrict__ bn_acc) {
    __shared__ float wlds[12288];
    int t = threadIdx.x;
    int j = t & 63;
    int jm = j & 15;
    int q = __builtin_amdgcn_readfirstlane(t >> 6);
    int n0 = blockIdx.x * 64;
    const float* Wp = W_post + (size_t)l * 832 * DD;
    float a1[8], a2[8], a3[8];
#pragma unroll
    for (int i = 0; i < 8; ++i) { a1[i] = 0.f; a2[i] = 0.f; a3[i] = 0.f; }
    for (int kc = 0; kc < 4; ++kc) {
        __syncthreads();
#pragma unroll
        for (int p = 0; p < 24; ++p) {
            int c = p >> 3;
            int k = ((p & 7) << 3) + (t >> 6);
            int rowbase = (c == 0) ? 64 : (c == 1 ? 320 : 576);
            float v = Wp[(size_t)(rowbase + kc * 64 + k) * 64 + j];
            wlds[c * 4096 + j * 64 + ((((k >> 2) ^ jm) << 2) | (k & 3))] = v;
        }
        __syncthreads();
        const float* ag = agg + (size_t)(n0 + q * 8) * 256 + kc * 64;
#pragma unroll 4
        for (int k4 = 0; k4 < 16; ++k4) {
            int widx = j * 64 + ((k4 ^ jm) << 2);
            float4 w1 = *(const float4*)&wlds[widx];
            float4 w2 = *(const float4*)&wlds[4096 + widx];
            float4 w3 = *(const float4*)&wlds[8192 + widx];
#pragma unroll
            for (int i = 0; i < 8; ++i) {
                float4 a = *(const float4*)(ag + (size_t)i * 256 + (k4 << 2));
                a1[i] = fmaf(a.w, w1.w, fmaf(a.z, w1.z, fmaf(a.y, w1.y, fmaf(a.x, w1.x, a1[i]))));
                a2[i] = fmaf(a.w, w2.w, fmaf(a.z, w2.z, fmaf(a.y, w2.y, fmaf(a.x, w2.x, a2[i]))));
                a3[i] = fmaf(a.w, w3.w, fmaf(a.z, w3.z, fmaf(a.y, w3.y, fmaf(a.x, w3.x, a3[i]))));
            }
        }
    }
    float bp = b_post[l * DD + j];
    float ps = 0.f, pss = 0.f;
#pragma unroll
    for (int i = 0; i < 8; ++i) {
        int n = n0 + q * 8 + i;
        float o = base_i[(size_t)n * DD + j] + bp + a1[i] + amp[n] * a2[i] + att[n] * a3[i];
        o *= snorm[n];
        h_pre[(size_t)n * DD + j] = o;
        ps += o;
        pss = fmaf(o, o, pss);
    }
    __syncthreads();
    wlds[t] = ps;
    wlds[512 + t] = pss;
    __syncthreads();
    if (t < 64) {
        float s = 0.f, s2 = 0.f;
#pragma unroll
        for (int w = 0; w < 8; ++w) { s += wlds[w * 64 + t]; s2 += wlds[512 + w * 64 + t]; }
        atomicAdd(&bn_acc[l * 128 + t], s);
        atomicAdd(&bn_acc[l * 128 + 64 + t], s2);
    }
}

// D: batchnorm finalize + relu + residual (in-place into h)
__global__ void k_D(const float* __restrict__ h_pre, const float* __restrict__ bn_acc, int l,
                    const float* __restrict__ gamma, const float* __restrict__ beta,
                    float* __restrict__ h) {
    int t = blockIdx.x * 256 + threadIdx.x;   // NN*DD
    int j = t & 63;
    float mu = bn_acc[l * 128 + j] * (1.0f / NN);
    float var = bn_acc[l * 128 + 64 + j] * (1.0f / NN) - mu * mu;
    float inv = rsqrtf(var + BN_EPS);
    float v = gamma[l * DD + j] * (h_pre[t] - mu) * inv + beta[l * DD + j];
    v = fmaxf(v, 0.f);
    h[t] = h[t] + v;
}

// readout: per-graph mean (128 consecutive nodes) + MLP 64->32->16->1
__global__ __launch_bounds__(64) void k_read(const float* __restrict__ h,
                                             const float* __restrict__ W1, const float* __restrict__ b1,
                                             const float* __restrict__ W2, const float* __restrict__ b2,
                                             const float* __restrict__ W3, const float* __restrict__ b3,
                                             float* __restrict__ out) {
    __shared__ float hgs[64];
    __shared__ float o1[32];
    __shared__ float o2[16];
    int g = blockIdx.x, lane = threadIdx.x;
    float acc = 0.f;
    for (int i = 0; i < 128; i++) acc += h[(size_t)(g * 128 + i) * DD + lane];
    hgs[lane] = acc * (1.0f / 128.0f);
    __syncthreads();
    if (lane < 32) {
        float s = b1[lane];
#pragma unroll
        for (int k = 0; k < 64; k++) s = fmaf(hgs[k], W1[k * 32 + lane], s);
        o1[lane] = fmaxf(s, 0.f);
    }
    __syncthreads();
    if (lane < 16) {
        float s = b2[lane];
#pragma unroll
        for (int k = 0; k < 32; k++) s = fmaf(o1[k], W2[k * 16 + lane], s);
        o2[lane] = fmaxf(s, 0.f);
    }
    __syncthreads();
    if (lane == 0) {
        float s = b3[0];
#pragma unroll
        for (int k = 0; k < 16; k++) s = fmaf(o2[k], W3[k], s);
        out[g] = s;
    }
}

// ---------------- launch ----------------

extern "C" void kernel_launch(void* const* d_in, const int* in_sizes, int n_in,
                              void* d_out, int out_size, void* d_ws, size_t ws_size,
                              hipStream_t stream) {
    const int* h_tok = (const int*)d_in[0];
    const int* e_tok = (const int*)d_in[1];
    const int* src = (const int*)d_in[2];
    const int* dst = (const int*)d_in[3];
    // d_in[4] graph_id: structure known (n/128)
    const float* snorm = (const float*)d_in[5];
    const float* emb_h = (const float*)d_in[6];
    const float* emb_e = (const float*)d_in[7];
    const float* W_pre = (const float*)d_in[8];
    const float* b_pre = (const float*)d_in[9];
    const float* W_post = (const float*)d_in[10];
    const float* b_post = (const float*)d_in[11];
    const float* gamma = (const float*)d_in[12];
    const float* beta = (const float*)d_in[13];
    const float* W1 = (const float*)d_in[14];
    const float* b1 = (const float*)d_in[15];
    const float* W2 = (const float*)d_in[16];
    const float* b2 = (const float*)d_in[17];
    const float* W3 = (const float*)d_in[18];
    const float* b3 = (const float*)d_in[19];
    float* out = (float*)d_out;

    char* ws = (char*)d_ws;
    size_t off = 0;
    auto alloc = [&](size_t bytes) {
        void* p = ws + off;
        off += (bytes + 255) & ~(size_t)255;
        return p;
    };
    float* h_cur = (float*)alloc((size_t)NN * DD * 4);
    float* h_pre = (float*)alloc((size_t)NN * DD * 4);
    float* ts = (float*)alloc((size_t)NN * DD * 4);
    float* td = (float*)alloc((size_t)NN * DD * 4);
    float* base_b = (float*)alloc((size_t)NN * DD * 4);
    float* agg = (float*)alloc((size_t)NN * 256 * 4);
    int* deg = (int*)alloc((size_t)NN * 4);
    int* row_start = (int*)alloc((size_t)(NN + 1) * 4);
    int* cursor = (int*)alloc((size_t)NN * 4);
    int* csr = (int*)alloc((size_t)NE * 4);
    float* amp = (float*)alloc((size_t)NN * 4);
    float* att = (float*)alloc((size_t)NN * 4);
    float* invdeg = (float*)alloc((size_t)NN * 4);
    float* bond = (float*)alloc((size_t)NL * 8 * DD * 4);
    float* bn_acc = (float*)alloc((size_t)NL * 128 * 4);

    hipMemsetAsync(deg, 0, (size_t)NN * 4, stream);
    hipMemsetAsync(bn_acc, 0, (size_t)NL * 128 * 4, stream);

    k_embed<<<NN * DD / 256, 256, 0, stream>>>(h_tok, emb_h, h_cur);
    k_deg<<<NE / 256, 256, 0, stream>>>(dst, deg);
    k_scan<<<1, 1024, 0, stream>>>(deg, row_start, cursor, amp, att, invdeg);
    k_scatter<<<NE / 256, 256, 0, stream>>>(src, dst, e_tok, cursor, csr);
    k_bond<<<NL * 8 * DD / 256, 256, 0, stream>>>(emb_e, W_pre, b_pre, bond);

    for (int l = 0; l < NL; l++) {
        k_A<<<NN / 64, 512, 0, stream>>>(h_cur, W_pre, W_post, l, ts, td, base_b);
        k_B<<<NN / 4, 256, 0, stream>>>(ts, td, bond + l * 8 * DD, row_start, csr, invdeg, agg);
        k_C<<<NN / 64, 512, 0, stream>>>(agg, base_b, W_post, b_post, l, amp, att, snorm,
                                         h_pre, bn_acc);
        k_D<<<NN * DD / 256, 256, 0, stream>>>(h_pre, bn_acc, l, gamma, beta, h_cur);
    }
    k_read<<<NG, 64, 0, stream>>>(h_cur, W1, b1, W2, b2, W3, b3, out);
}